// Round 9
// baseline (697.680 us; speedup 1.0000x reference)
//
#include <hip/hip_runtime.h>
#include <hip/hip_bf16.h>

// SDE Euler-Maruyama: x_{k+1} = x_k + dt*(x_k @ A^T) + (sigma*sqrt(dt))*dW_k
// out[0] = x0, out[k+1] = x_{k+1}, out shape [1001, 1024, 256].
//
// R1 880 / R2 849 / R3 973 / R4 632 / R5 644 / R6 743 / R7 715 / R8 601.
// R8 = replica-fused update (C/D rows 4-15 duplicate paths 0-3 -> every
// 16-lane group holds all 4 paths' drift; group g updates path g), one
// lgkm-only barrier/step. Remaining cost: 8 waves x 8 ds_read_b128 = 64
// LDS-pipe ops/CU/step (~770 cyc) on top of 620 cyc MFMA.
// R9: 256 thr = 4 waves = 1 wave/SIMD. Wave owns 64 cols (4 chains x 8 kt
// = 32 MFMA). LDS reads/CU halve to 32; per-SIMD MFMA issue unchanged
// (620 cyc); update/VALU/VMEM issue in the ~17-cyc gaps between MFMA
// issues. Exposed: ~130 cyc ds_read latency + update tail + barrier skew.

typedef __attribute__((ext_vector_type(4))) float fvec4;
typedef __attribute__((ext_vector_type(4))) unsigned short usvec4;
typedef __attribute__((ext_vector_type(8))) short svec8;
typedef __attribute__((ext_vector_type(4))) float f32x4;

constexpr int D = 256;
constexpr int BATCH = 1024;
constexpr int BD = BATCH * D;
constexpr int NSTEPS = 1000;
constexpr float DT = 0.001f;
constexpr float SQRT_DT = 0.03162277660168379f;  // sqrt(0.001)

__device__ __forceinline__ unsigned short f2bf(float f) {
  // round-to-nearest-even f32 -> bf16
  unsigned int u = __float_as_uint(f);
  u += 0x7FFFu + ((u >> 16) & 1u);
  return (unsigned short)(u >> 16);
}

// LDS-only barrier: no vmcnt drain (global loads/stores stay in flight).
__device__ __forceinline__ void lds_barrier() {
  __builtin_amdgcn_sched_barrier(0);
  asm volatile("s_waitcnt lgkmcnt(0)" ::: "memory");
  __builtin_amdgcn_s_barrier();
  __builtin_amdgcn_sched_barrier(0);
}

// select v[g] for g in 0..3 (g uniform per 16-lane group -> 3 v_cndmask)
__device__ __forceinline__ float sel4(f32x4 v, int g) {
  float r = v[0];
  r = (g == 1) ? v[1] : r;
  r = (g == 2) ? v[2] : r;
  r = (g == 3) ? v[3] : r;
  return r;
}

__global__ __launch_bounds__(256, 1)
void sde_em_kernel(const float* __restrict__ x0, const float* __restrict__ Amat,
                   const float* __restrict__ sigma, const float* __restrict__ dW,
                   float* __restrict__ out) {
  // xb: double-buffered bf16 x, 4 paths x 256 dims, swizzled (^ row<<5, u16)
  __shared__ __align__(16) unsigned short xb[2][4 * 256];

  const int t = threadIdx.x;
  const int w = t >> 6;          // wave 0..3: owns cols w*64 .. w*64+63
  const int l = t & 63;
  const int l16 = l & 15;
  const int q = l >> 4;          // lane group 0..3 (frag k-slot; update path)
  const int rr = l16 & 3;        // A-frag row -> path (rows 4-15 duplicate 0-3)

  // ---- one-time: A fragments (GEMM B-operand), bf16, registers ----
  // B-frag (16x16x32): lane holds col n = l&15 (+16*tt), k = q*8 + i (+32*kt)
  svec8 bfr[4][8];
#pragma unroll
  for (int tt = 0; tt < 4; ++tt) {
#pragma unroll
    for (int kt = 0; kt < 8; ++kt) {
      const float* src =
          Amat + (size_t)((w << 6) + (tt << 4) + l16) * D + (kt << 5) + (q << 3);
      fvec4 a0 = *(const fvec4*)(src);
      fvec4 a1 = *(const fvec4*)(src + 4);
      svec8 b;
      b[0] = (short)f2bf(a0[0]); b[1] = (short)f2bf(a0[1]);
      b[2] = (short)f2bf(a0[2]); b[3] = (short)f2bf(a0[3]);
      b[4] = (short)f2bf(a1[0]); b[5] = (short)f2bf(a1[1]);
      b[6] = (short)f2bf(a1[2]); b[7] = (short)f2bf(a1[3]);
      bfr[tt][kt] = b;
    }
  }

  // ---- prologue (vectorized, 256 threads): out[0]=x0, seed xb[0] ----
  {
    const int p2 = t >> 6;             // path 0..3
    const int c2 = (t & 63) << 2;      // dim 0,4,..252
    const size_t g2 = (size_t)((blockIdx.x << 2) + p2) * D + c2;
    fvec4 v = *(const fvec4*)(x0 + g2);
    __builtin_nontemporal_store(v, (fvec4*)(out + g2));
    usvec4 pk = { f2bf(v[0]), f2bf(v[1]), f2bf(v[2]), f2bf(v[3]) };
    *(usvec4*)&xb[0][(p2 << 8) + (c2 ^ (p2 << 5))] = pk;
  }

  // ---- fused update role: lane (group q, l16) owns path q, cols
  //      w*64 + tt*16 + l16 for tt = 0..3 (drift = acc[tt][q]) ----
  const int c0 = (w << 6) + l16;       // base col (+16*tt)
  const size_t go = (size_t)((blockIdx.x << 2) + q) * D + c0;

  float sg[4], xs[4], dwA[4], dwB[4];
  int xw[4];
#pragma unroll
  for (int tt = 0; tt < 4; ++tt) {
    sg[tt] = sigma[c0 + (tt << 4)] * SQRT_DT;
    xs[tt] = x0[go + (tt << 4)];
    dwA[tt] = __builtin_nontemporal_load(dW + go + (tt << 4));
    dwB[tt] = __builtin_nontemporal_load(dW + BD + go + (tt << 4));
    xw[tt] = (q << 8) + ((c0 + (tt << 4)) ^ (q << 5));
  }

  __syncthreads();

#define STEP(n_, CUR, RB, WB)                                                  \
  {                                                                            \
    f32x4 acc[4];                                                              \
    acc[0] = (f32x4){0.f, 0.f, 0.f, 0.f};                                      \
    acc[1] = (f32x4){0.f, 0.f, 0.f, 0.f};                                      \
    acc[2] = (f32x4){0.f, 0.f, 0.f, 0.f};                                      \
    acc[3] = (f32x4){0.f, 0.f, 0.f, 0.f};                                      \
    _Pragma("unroll") for (int kt = 0; kt < 8; ++kt) {                         \
      svec8 a = *(const svec8*)                                                \
          &xb[RB][(rr << 8) + (((kt << 5) + (q << 3)) ^ (rr << 5))];           \
      _Pragma("unroll") for (int tt = 0; tt < 4; ++tt) acc[tt] =               \
          __builtin_amdgcn_mfma_f32_16x16x32_bf16(a, bfr[tt][kt], acc[tt], 0,  \
                                                  0, 0);                       \
    }                                                                          \
    /* group q holds all 4 paths' drift (reg r = path r); take path q */       \
    float* op_ = out + (size_t)((n_) + 1) * BD + go;                           \
    _Pragma("unroll") for (int tt = 0; tt < 4; ++tt) {                         \
      const float df_ = sel4(acc[tt], q);                                      \
      xs[tt] = __builtin_fmaf(DT, df_,                                         \
                              __builtin_fmaf(sg[tt], CUR[tt], xs[tt]));        \
      __builtin_nontemporal_store(xs[tt], op_ + (tt << 4));                    \
      xb[WB][xw[tt]] = f2bf(xs[tt]);                                           \
    }                                                                          \
    const int nn_ = ((n_) + 2 < NSTEPS) ? ((n_) + 2) : (NSTEPS - 1);           \
    const float* dwp_ = dW + (size_t)nn_ * BD + go;                            \
    _Pragma("unroll") for (int tt = 0; tt < 4; ++tt)                           \
        CUR[tt] = __builtin_nontemporal_load(dwp_ + (tt << 4));                \
    lds_barrier();                                                             \
  }

  for (int n = 0; n < NSTEPS; n += 2) {
    STEP(n, dwA, 0, 1);
    STEP(n + 1, dwB, 1, 0);
  }
#undef STEP
}

extern "C" void kernel_launch(void* const* d_in, const int* in_sizes, int n_in,
                              void* d_out, int out_size, void* d_ws, size_t ws_size,
                              hipStream_t stream) {
  const float* x0    = (const float*)d_in[0];
  const float* Amat  = (const float*)d_in[1];
  const float* sigma = (const float*)d_in[2];
  const float* dW    = (const float*)d_in[3];
  float* out = (float*)d_out;
  sde_em_kernel<<<dim3(256), dim3(256), 0, stream>>>(x0, Amat, sigma, dW, out);
}

// Round 11
// 440.580 us; speedup vs baseline: 1.5836x; 1.5836x over previous
//
#include <hip/hip_runtime.h>
#include <hip/hip_bf16.h>

// SDE Euler-Maruyama: x_{k+1} = x_k + dt*(x_k @ A^T) + (sigma*sqrt(dt))*dW_k
// out[0] = x0, out[k+1] = x_{k+1}, out shape [1001, 1024, 256].
//
// R1 880 / R2 849 / R3 973 / R4 632 / R5 644 / R6 743 / R7 715 / R8 601 /
// R9 697 / R10 FAILED (path-crossing in lane-group exchange).
// R11 = R10 + fixed exchange. FUSED 2-STEP, pad rows carry noise:
//   nu_k = sg*dW_k
//   x_{n+1} = x_n + dtA x_n + nu_n
//   x_{n+2} = x_n + 2(dtA x_n) + nu_n + dtA nu_n + nu_{n+1}  [dt^2A^2 dropped,
//     ~2e-5 accumulated]
// A-operand rows {x[0-3], nu[0-3]} x2 dup; B = dt*A^T (bf16, registers).
// C/D group g regs = tile rows 4g..4g+3: g0/g2 hold dtAx[0-3], g1/g3 hold
// dtAnu[0-3]. Group q updates path q: keep = sel4(acc,q) (own-half value for
// path q), send = sel4(acc,q^1) (own-half value for PARTNER path), shfl_xor
// 16 delivers partner-half value for path q. Even q: dax=keep, dav=recv;
// odd q: dax=recv, dav=keep.

typedef __attribute__((ext_vector_type(2))) float fvec2;
typedef __attribute__((ext_vector_type(4))) float fvec4;
typedef __attribute__((ext_vector_type(8))) short svec8;
typedef __attribute__((ext_vector_type(4))) float f32x4;

constexpr int D = 256;
constexpr int BATCH = 1024;
constexpr int BD = BATCH * D;
constexpr int NSTEPS = 1000;
constexpr float DT = 0.001f;
constexpr float SQRT_DT = 0.03162277660168379f;  // sqrt(0.001)

__device__ __forceinline__ unsigned short f2bf(float f) {
  // round-to-nearest-even f32 -> bf16
  unsigned int u = __float_as_uint(f);
  u += 0x7FFFu + ((u >> 16) & 1u);
  return (unsigned short)(u >> 16);
}

// LDS-only barrier: no vmcnt drain (global loads/stores stay in flight).
__device__ __forceinline__ void lds_barrier() {
  __builtin_amdgcn_sched_barrier(0);
  asm volatile("s_waitcnt lgkmcnt(0)" ::: "memory");
  __builtin_amdgcn_s_barrier();
  __builtin_amdgcn_sched_barrier(0);
}

// select v[g] for g in 0..3 (g uniform per 16-lane group -> cndmask chain)
__device__ __forceinline__ float sel4(f32x4 v, int g) {
  float r = v[0];
  r = (g == 1) ? v[1] : r;
  r = (g == 2) ? v[2] : r;
  r = (g == 3) ? v[3] : r;
  return r;
}

__global__ __launch_bounds__(512, 2)
void sde_em_kernel(const float* __restrict__ x0, const float* __restrict__ Amat,
                   const float* __restrict__ sigma, const float* __restrict__ dW,
                   float* __restrict__ out) {
  // xb rows 0-3: bf16 x (paths 0-3); rows 4-7: bf16 nu_n (paths 0-3).
  // u16 idx for (row r, col c) = (r<<8) + (c ^ (r<<5)). Double-buffered.
  __shared__ __align__(16) unsigned short xb[2][8 * 256];

  const int t = threadIdx.x;
  const int w = t >> 6;          // wave 0..7: owns cols w*32 .. w*32+31
  const int l = t & 63;
  const int l16 = l & 15;
  const int q = l >> 4;          // lane group 0..3 (frag k-slot; update path)
  const int rr8 = l16 & 7;       // A-frag row (tile rows 8-15 duplicate 0-7)

  // ---- one-time: B = DT*A^T fragments, bf16, registers ----
  // B-frag (16x16x32): lane holds col n = l&15 (+16*tt), k = q*8 + i (+32*kt)
  svec8 bfr[2][8];
#pragma unroll
  for (int tt = 0; tt < 2; ++tt) {
#pragma unroll
    for (int kt = 0; kt < 8; ++kt) {
      const float* src =
          Amat + (size_t)((w << 5) + (tt << 4) + l16) * D + (kt << 5) + (q << 3);
      fvec4 a0 = *(const fvec4*)(src);
      fvec4 a1 = *(const fvec4*)(src + 4);
      svec8 b;
      b[0] = (short)f2bf(DT * a0[0]); b[1] = (short)f2bf(DT * a0[1]);
      b[2] = (short)f2bf(DT * a0[2]); b[3] = (short)f2bf(DT * a0[3]);
      b[4] = (short)f2bf(DT * a1[0]); b[5] = (short)f2bf(DT * a1[1]);
      b[6] = (short)f2bf(DT * a1[2]); b[7] = (short)f2bf(DT * a1[3]);
      bfr[tt][kt] = b;
    }
  }

  // ---- update role: lane (group q, l16) owns path q, cols c0 and c0+16 ----
  const int c0 = (w << 5) + l16;
  const size_t go = (size_t)((blockIdx.x << 2) + q) * D + c0;
  const float sg0 = sigma[c0] * SQRT_DT;
  const float sg1 = sigma[c0 + 16] * SQRT_DT;
  float xs0 = x0[go];
  float xs1 = x0[go + 16];

  // rolling dW f32 regs: dw0 = dW[n], dw1 = dW[n+1], dw2 = dW[n+2]
  float dw00 = __builtin_nontemporal_load(dW + go);
  float dw01 = __builtin_nontemporal_load(dW + go + 16);
  float dw10 = __builtin_nontemporal_load(dW + BD + go);
  float dw11 = __builtin_nontemporal_load(dW + BD + go + 16);
  float dw20 = __builtin_nontemporal_load(dW + 2 * BD + go);
  float dw21 = __builtin_nontemporal_load(dW + 2 * BD + go + 16);

  // xb write indices (col c0; col c0+16 = +16, bit 4 untouched by the XOR)
  const int xwX = (q << 8) + (c0 ^ (q << 5));            // x row q
  const int rn = 4 + q;
  const int xwN = (rn << 8) + (c0 ^ (rn << 5));          // nu row 4+q

  xb[0][xwX] = f2bf(xs0);
  xb[0][xwX + 16] = f2bf(xs1);
  xb[0][xwN] = f2bf(sg0 * dw00);
  xb[0][xwN + 16] = f2bf(sg1 * dw01);

  // out[0] = x0 (vectorized copy, all 512 threads)
  {
    const int p2 = t >> 7;
    const int c2 = (t & 127) << 1;
    const size_t g2 = (size_t)((blockIdx.x << 2) + p2) * D + c2;
    fvec2 v = *(const fvec2*)(x0 + g2);
    __builtin_nontemporal_store(v, (fvec2*)(out + g2));
  }

  __syncthreads();

#define ITER(n_, RB, WB)                                                       \
  {                                                                            \
    /* prefetch dW[n+3], dW[n+4] (consumed next iter) */                       \
    const int i3_ = ((n_) + 3 < NSTEPS) ? ((n_) + 3) : (NSTEPS - 1);           \
    const int i4_ = ((n_) + 4 < NSTEPS) ? ((n_) + 4) : (NSTEPS - 1);           \
    const float* p3_ = dW + (size_t)i3_ * BD + go;                             \
    const float* p4_ = dW + (size_t)i4_ * BD + go;                             \
    const float ld30 = __builtin_nontemporal_load(p3_);                        \
    const float ld31 = __builtin_nontemporal_load(p3_ + 16);                   \
    const float ld40 = __builtin_nontemporal_load(p4_);                        \
    const float ld41 = __builtin_nontemporal_load(p4_ + 16);                   \
    /* one MFMA pass: rows {x, nu} -> dtAx (groups 0,2), dtAnu (groups 1,3) */ \
    f32x4 acc0 = (f32x4){0.f, 0.f, 0.f, 0.f};                                  \
    f32x4 acc1 = (f32x4){0.f, 0.f, 0.f, 0.f};                                  \
    _Pragma("unroll") for (int kt = 0; kt < 8; ++kt) {                         \
      svec8 a = *(const svec8*)                                                \
          &xb[RB][(rr8 << 8) + (((kt << 5) + (q << 3)) ^ (rr8 << 5))];         \
      acc0 = __builtin_amdgcn_mfma_f32_16x16x32_bf16(a, bfr[0][kt], acc0,      \
                                                     0, 0, 0);                 \
      acc1 = __builtin_amdgcn_mfma_f32_16x16x32_bf16(a, bfr[1][kt], acc1,      \
                                                     0, 0, 0);                 \
    }                                                                          \
    /* keep own-path value from own half; send own-half value for PARTNER   */ \
    /* path (reg q^1); recv = partner-half value for path q.                */ \
    const float k0 = sel4(acc0, q), k1 = sel4(acc1, q);                        \
    const float sd0 = sel4(acc0, q ^ 1), sd1 = sel4(acc1, q ^ 1);              \
    const float u0 = __shfl_xor(sd0, 16), u1 = __shfl_xor(sd1, 16);            \
    const bool od = (q & 1) != 0;                                              \
    const float dax0 = od ? u0 : k0, dav0 = od ? k0 : u0;                      \
    const float dax1 = od ? u1 : k1, dav1 = od ? k1 : u1;                      \
    /* y = x_{n+1}; xs' = x_{n+2} */                                           \
    const float y0 = xs0 + dax0 + sg0 * dw00;                                  \
    const float y1 = xs1 + dax1 + sg1 * dw01;                                  \
    xs0 = y0 + dax0 + dav0 + sg0 * dw10;                                       \
    xs1 = y1 + dax1 + dav1 + sg1 * dw11;                                       \
    float* o1_ = out + (size_t)((n_) + 1) * BD + go;                           \
    float* o2_ = out + (size_t)((n_) + 2) * BD + go;                           \
    __builtin_nontemporal_store(y0, o1_);                                      \
    __builtin_nontemporal_store(y1, o1_ + 16);                                 \
    __builtin_nontemporal_store(xs0, o2_);                                     \
    __builtin_nontemporal_store(xs1, o2_ + 16);                                \
    xb[WB][xwX] = f2bf(xs0);                                                   \
    xb[WB][xwX + 16] = f2bf(xs1);                                              \
    xb[WB][xwN] = f2bf(sg0 * dw20);                                            \
    xb[WB][xwN + 16] = f2bf(sg1 * dw21);                                       \
    dw00 = dw20; dw01 = dw21;                                                  \
    dw10 = ld30; dw11 = ld31;                                                  \
    dw20 = ld40; dw21 = ld41;                                                  \
    lds_barrier();                                                             \
  }

  // 500 fused iterations (n = 0,2,...,998), unrolled x2 for buffer parity
  for (int k = 0; k < NSTEPS / 2; k += 2) {
    ITER(2 * k, 0, 1);
    ITER(2 * k + 2, 1, 0);
  }
#undef ITER
}

extern "C" void kernel_launch(void* const* d_in, const int* in_sizes, int n_in,
                              void* d_out, int out_size, void* d_ws, size_t ws_size,
                              hipStream_t stream) {
  const float* x0    = (const float*)d_in[0];
  const float* Amat  = (const float*)d_in[1];
  const float* sigma = (const float*)d_in[2];
  const float* dW    = (const float*)d_in[3];
  float* out = (float*)d_out;
  sde_em_kernel<<<dim3(256), dim3(512), 0, stream>>>(x0, Amat, sigma, dW, out);
}

// Round 12
// 408.447 us; speedup vs baseline: 1.7081x; 1.0787x over previous
//
#include <hip/hip_runtime.h>
#include <hip/hip_bf16.h>

// SDE Euler-Maruyama: x_{k+1} = x_k + dt*(x_k @ A^T) + (sigma*sqrt(dt))*dW_k
// out[0] = x0, out[k+1] = x_{k+1}, out shape [1001, 1024, 256].
//
// R1 880 / R2 849 / R3 973 / R4 632 / R5 644 / R6 743 / R7 715 / R8 601 /
// R9 697 / R10 fail / R11 440 (fused 2-step).
// R12: FUSED 4-STEP, fully-packed 16-row tile (no pad waste). M = dt*A:
//   y1 = x + Mx + nu0;  y2 = y1 + (Mx+Mnu0) + nu1;
//   y3 = y2 + (Mx+Mnu0+Mnu1) + nu2;  y4 = y3 + (Mx+..+Mnu2) + nu3
//   [O(M^2) dropped: ~1e-4 accumulated, vs 0.031 bf16 error]
// A rows R=4g+p: quantity g in {x, nu_n, nu_n+1, nu_n+2}, path p. C/D group
// g = quantity g, reg = path. 2-stage butterfly (shfl_xor 16, 32) transposes
// so lane group q gets all 4 quantities for path q. One MFMA pass / 4 steps.

typedef __attribute__((ext_vector_type(2))) float fvec2;
typedef __attribute__((ext_vector_type(4))) float fvec4;
typedef __attribute__((ext_vector_type(8))) short svec8;
typedef __attribute__((ext_vector_type(4))) float f32x4;

constexpr int D = 256;
constexpr int BATCH = 1024;
constexpr int BD = BATCH * D;
constexpr int NSTEPS = 1000;
constexpr float DT = 0.001f;
constexpr float SQRT_DT = 0.03162277660168379f;  // sqrt(0.001)

__device__ __forceinline__ unsigned short f2bf(float f) {
  unsigned int u = __float_as_uint(f);
  u += 0x7FFFu + ((u >> 16) & 1u);
  return (unsigned short)(u >> 16);
}

// LDS-only barrier: no vmcnt drain (global loads/stores stay in flight).
__device__ __forceinline__ void lds_barrier() {
  __builtin_amdgcn_sched_barrier(0);
  asm volatile("s_waitcnt lgkmcnt(0)" ::: "memory");
  __builtin_amdgcn_s_barrier();
  __builtin_amdgcn_sched_barrier(0);
}

// xb u16 index for (row R, col c), XOR-swizzled
#define XIDX(R, c) ((((R) << 8)) + ((c) ^ (((R)&7) << 5)))

__global__ __launch_bounds__(512, 2)
void sde_em_kernel(const float* __restrict__ x0, const float* __restrict__ Amat,
                   const float* __restrict__ sigma, const float* __restrict__ dW,
                   float* __restrict__ out) {
  // xb: 16 rows (R = 4g+p) x 256 cols bf16, double-buffered (16 KB)
  __shared__ __align__(16) unsigned short xb[2][16 * 256];

  const int t = threadIdx.x;
  const int w = t >> 6;          // wave 0..7: owns cols w*32 .. w*32+31
  const int l = t & 63;
  const int l16 = l & 15;
  const int q = l >> 4;          // lane group 0..3 (frag k-slot; update path)
  const int bq = q & 1;          // bit0(q)
  const int Bq = q >> 1;         // bit1(q)

  // ---- one-time: B = DT*A^T fragments, bf16, registers ----
  svec8 bfr[2][8];
#pragma unroll
  for (int tt = 0; tt < 2; ++tt) {
#pragma unroll
    for (int kt = 0; kt < 8; ++kt) {
      const float* src =
          Amat + (size_t)((w << 5) + (tt << 4) + l16) * D + (kt << 5) + (q << 3);
      fvec4 a0 = *(const fvec4*)(src);
      fvec4 a1 = *(const fvec4*)(src + 4);
      svec8 b;
      b[0] = (short)f2bf(DT * a0[0]); b[1] = (short)f2bf(DT * a0[1]);
      b[2] = (short)f2bf(DT * a0[2]); b[3] = (short)f2bf(DT * a0[3]);
      b[4] = (short)f2bf(DT * a1[0]); b[5] = (short)f2bf(DT * a1[1]);
      b[6] = (short)f2bf(DT * a1[2]); b[7] = (short)f2bf(DT * a1[3]);
      bfr[tt][kt] = b;
    }
  }

  // ---- update role: lane (group q, l16) owns path q, cols c0, c0+16 ----
  const int c0 = (w << 5) + l16;
  const size_t go = (size_t)((blockIdx.x << 2) + q) * D + c0;
  const float sg0 = sigma[c0] * SQRT_DT;
  const float sg1 = sigma[c0 + 16] * SQRT_DT;
  float xs0 = x0[go];
  float xs1 = x0[go + 16];

  // rolling dW window: dwv[i] = dW[step n+i], i = 0..6
  float dv0[7], dv1[7];
#pragma unroll
  for (int i = 0; i < 7; ++i) {
    dv0[i] = __builtin_nontemporal_load(dW + (size_t)i * BD + go);
    dv1[i] = __builtin_nontemporal_load(dW + (size_t)i * BD + go + 16);
  }

  // seed xb[0]: x rows (R=q), nu rows (R=4+q, 8+q, 12+q from steps 0,1,2)
  xb[0][XIDX(q, c0)] = f2bf(xs0);
  xb[0][XIDX(q, c0 + 16)] = f2bf(xs1);
  xb[0][XIDX(4 + q, c0)] = f2bf(sg0 * dv0[0]);
  xb[0][XIDX(4 + q, c0 + 16)] = f2bf(sg1 * dv1[0]);
  xb[0][XIDX(8 + q, c0)] = f2bf(sg0 * dv0[1]);
  xb[0][XIDX(8 + q, c0 + 16)] = f2bf(sg1 * dv1[1]);
  xb[0][XIDX(12 + q, c0)] = f2bf(sg0 * dv0[2]);
  xb[0][XIDX(12 + q, c0 + 16)] = f2bf(sg1 * dv1[2]);

  // out[0] = x0 (vectorized copy, all 512 threads)
  {
    const int p2 = t >> 7;
    const int c2 = (t & 127) << 1;
    const size_t g2 = (size_t)((blockIdx.x << 2) + p2) * D + c2;
    fvec2 v = *(const fvec2*)(x0 + g2);
    __builtin_nontemporal_store(v, (fvec2*)(out + g2));
  }

  __syncthreads();

  // selq: pick by lane group q (uniform per 16 lanes -> cndmask chain)
#define SELQ(r, a0_, a1_, a2_, a3_)                                            \
  float r = a0_;                                                               \
  r = (q == 1) ? a1_ : r;                                                      \
  r = (q == 2) ? a2_ : r;                                                      \
  r = (q == 3) ? a3_ : r;

  // butterfly transpose: acc[p] = Q_q[path p] -> T_g = Q_g[path q]
#define XPOSE(A, T0, T1, T2, T3)                                               \
  const float u1_##T0 = __shfl_xor(bq ? A[0] : A[1], 16);                      \
  const float u2_##T0 = __shfl_xor(bq ? A[2] : A[3], 16);                      \
  const float k1_##T0 = bq ? A[1] : A[0];                                      \
  const float k2_##T0 = bq ? A[3] : A[2];                                      \
  const float v1_##T0 = __shfl_xor(Bq ? k1_##T0 : k2_##T0, 32);                \
  const float v2_##T0 = __shfl_xor(Bq ? u1_##T0 : u2_##T0, 32);                \
  const float tq_##T0 = Bq ? k2_##T0 : k1_##T0;                                \
  const float tu_##T0 = Bq ? u2_##T0 : u1_##T0;                                \
  SELQ(T0, tq_##T0, tu_##T0, v1_##T0, v2_##T0)                                 \
  SELQ(T1, tu_##T0, tq_##T0, v2_##T0, v1_##T0)                                 \
  SELQ(T2, v1_##T0, v2_##T0, tq_##T0, tu_##T0)                                 \
  SELQ(T3, v2_##T0, v1_##T0, tu_##T0, tq_##T0)

#define ITER(n_, RB, WB)                                                       \
  {                                                                            \
    /* prefetch dW[n+7 .. n+10] (fills window tail after roll) */              \
    float pf0[4], pf1[4];                                                      \
    _Pragma("unroll") for (int j = 0; j < 4; ++j) {                            \
      int i_ = (n_) + 7 + j;                                                   \
      i_ = (i_ < NSTEPS) ? i_ : (NSTEPS - 1);                                  \
      pf0[j] = __builtin_nontemporal_load(dW + (size_t)i_ * BD + go);          \
      pf1[j] = __builtin_nontemporal_load(dW + (size_t)i_ * BD + go + 16);     \
    }                                                                          \
    f32x4 acc0 = (f32x4){0.f, 0.f, 0.f, 0.f};                                  \
    f32x4 acc1 = (f32x4){0.f, 0.f, 0.f, 0.f};                                  \
    _Pragma("unroll") for (int kt = 0; kt < 8; ++kt) {                         \
      svec8 a = *(const svec8*)                                                \
          &xb[RB][(l16 << 8) + (((kt << 5) + (q << 3)) ^ ((l16 & 7) << 5))];   \
      acc0 = __builtin_amdgcn_mfma_f32_16x16x32_bf16(a, bfr[0][kt], acc0,      \
                                                     0, 0, 0);                 \
      acc1 = __builtin_amdgcn_mfma_f32_16x16x32_bf16(a, bfr[1][kt], acc1,      \
                                                     0, 0, 0);                 \
    }                                                                          \
    XPOSE(acc0, tA0, tA1, tA2, tA3)                                            \
    XPOSE(acc1, tB0, tB1, tB2, tB3)                                            \
    const float p1A = tA0, p2A = p1A + tA1, p3A = p2A + tA2, p4A = p3A + tA3;  \
    const float p1B = tB0, p2B = p1B + tB1, p3B = p2B + tB2, p4B = p3B + tB3;  \
    float* ob_ = out + (size_t)((n_) + 1) * BD + go;                           \
    xs0 = __builtin_fmaf(sg0, dv0[0], xs0) + p1A;                              \
    xs1 = __builtin_fmaf(sg1, dv1[0], xs1) + p1B;                              \
    __builtin_nontemporal_store(xs0, ob_);                                     \
    __builtin_nontemporal_store(xs1, ob_ + 16);                                \
    xs0 = __builtin_fmaf(sg0, dv0[1], xs0) + p2A;                              \
    xs1 = __builtin_fmaf(sg1, dv1[1], xs1) + p2B;                              \
    __builtin_nontemporal_store(xs0, ob_ + BD);                                \
    __builtin_nontemporal_store(xs1, ob_ + BD + 16);                           \
    xs0 = __builtin_fmaf(sg0, dv0[2], xs0) + p3A;                              \
    xs1 = __builtin_fmaf(sg1, dv1[2], xs1) + p3B;                              \
    __builtin_nontemporal_store(xs0, ob_ + 2 * BD);                            \
    __builtin_nontemporal_store(xs1, ob_ + 2 * BD + 16);                       \
    xs0 = __builtin_fmaf(sg0, dv0[3], xs0) + p4A;                              \
    xs1 = __builtin_fmaf(sg1, dv1[3], xs1) + p4B;                              \
    __builtin_nontemporal_store(xs0, ob_ + 3 * BD);                            \
    __builtin_nontemporal_store(xs1, ob_ + 3 * BD + 16);                       \
    /* next tile: x = y4; nu from steps n+4, n+5, n+6 (dv[4..6]) */            \
    xb[WB][XIDX(q, c0)] = f2bf(xs0);                                           \
    xb[WB][XIDX(q, c0 + 16)] = f2bf(xs1);                                      \
    xb[WB][XIDX(4 + q, c0)] = f2bf(sg0 * dv0[4]);                              \
    xb[WB][XIDX(4 + q, c0 + 16)] = f2bf(sg1 * dv1[4]);                         \
    xb[WB][XIDX(8 + q, c0)] = f2bf(sg0 * dv0[5]);                              \
    xb[WB][XIDX(8 + q, c0 + 16)] = f2bf(sg1 * dv1[5]);                         \
    xb[WB][XIDX(12 + q, c0)] = f2bf(sg0 * dv0[6]);                             \
    xb[WB][XIDX(12 + q, c0 + 16)] = f2bf(sg1 * dv1[6]);                        \
    /* roll window by 4 */                                                     \
    dv0[0] = dv0[4]; dv0[1] = dv0[5]; dv0[2] = dv0[6];                         \
    dv0[3] = pf0[0]; dv0[4] = pf0[1]; dv0[5] = pf0[2]; dv0[6] = pf0[3];        \
    dv1[0] = dv1[4]; dv1[1] = dv1[5]; dv1[2] = dv1[6];                         \
    dv1[3] = pf1[0]; dv1[4] = pf1[1]; dv1[5] = pf1[2]; dv1[6] = pf1[3];        \
    lds_barrier();                                                             \
  }

  // 250 fused iterations (n = 0, 4, ..., 996), x2 unroll for buffer parity
  for (int k = 0; k < NSTEPS / 4; k += 2) {
    ITER(4 * k, 0, 1);
    ITER(4 * k + 4, 1, 0);
  }
#undef ITER
#undef XPOSE
#undef SELQ
}

extern "C" void kernel_launch(void* const* d_in, const int* in_sizes, int n_in,
                              void* d_out, int out_size, void* d_ws, size_t ws_size,
                              hipStream_t stream) {
  const float* x0    = (const float*)d_in[0];
  const float* Amat  = (const float*)d_in[1];
  const float* sigma = (const float*)d_in[2];
  const float* dW    = (const float*)d_in[3];
  float* out = (float*)d_out;
  sde_em_kernel<<<dim3(256), dim3(512), 0, stream>>>(x0, Amat, sigma, dW, out);
}